// Round 9
// baseline (165.667 us; speedup 1.0000x reference)
//
#include <hip/hip_runtime.h>

#define N_PTS 8192
#define BATCH 2
#define KNN 8
#define STILE 2048                      // LDS tile (points) for both roles
#define SM_PPW 8                        // smooth points per wave
#define SM_PPB 32                       // smooth points per block
#define SM_BLOCKS (BATCH * N_PTS / SM_PPB)   // 512
#define CH_ROWS 256                     // chamfer rows per block
#define CH_BLOCKS (4 * N_PTS / CH_ROWS)      // 128 (4 combos x 32)

// ---------------- helpers ----------------
__device__ __forceinline__ void ce(unsigned &x, unsigned &y) {
    unsigned lo = min(x, y), hi = max(x, y); x = lo; y = hi;
}

__device__ __forceinline__ void insert4(unsigned o[4], unsigned key) {
    unsigned n0 = min(o[0], key);
    unsigned n1 = max(o[0], min(o[1], key));
    unsigned n2 = max(o[1], min(o[2], key));
    unsigned n3 = max(o[2], min(o[3], key));
    o[0]=n0; o[1]=n1; o[2]=n2; o[3]=n3;
}

__device__ __forceinline__ void merge_stage8(unsigned m[8], int d) {
    unsigned p[8], c[8];
    #pragma unroll
    for (int k = 0; k < 8; ++k) p[k] = (unsigned)__shfl_xor((int)m[k], d, 64);
    #pragma unroll
    for (int k = 0; k < 8; ++k) c[k] = min(m[k], p[7-k]);
    ce(c[0],c[4]); ce(c[1],c[5]); ce(c[2],c[6]); ce(c[3],c[7]);
    ce(c[0],c[2]); ce(c[1],c[3]); ce(c[4],c[6]); ce(c[5],c[7]);
    ce(c[0],c[1]); ce(c[2],c[3]); ce(c[4],c[5]); ce(c[6],c[7]);
    #pragma unroll
    for (int k = 0; k < 8; ++k) m[k] = c[k];
}

__device__ __forceinline__ void merge64(unsigned m[8]) {
    merge_stage8(m, 1); merge_stage8(m, 2); merge_stage8(m, 4);
    merge_stage8(m, 8); merge_stage8(m, 16); merge_stage8(m, 32);
}

// ---------------- mega: 512 smooth blocks + 128 chamfer blocks ----------------
__global__ __launch_bounds__(256, 4) void mega_kernel(
        const float* __restrict__ pc1, const float* __restrict__ pc2,
        const float* __restrict__ flow, float* __restrict__ out) {
    __shared__ float4 sq[STILE];   // 32 KiB
    __shared__ float psum[4];
    const int tid = threadIdx.x;
    const int bx = blockIdx.x;

    if (bx < SM_BLOCKS) {
        // ================= smooth role: wave owns 8 points =================
        const int b = bx >> 8, sx = bx & 255;
        const int wv = tid >> 6, lane = tid & 63;
        const int i0w = sx * SM_PPB + wv * SM_PPW;
        const float* P = pc1  + (size_t)b * N_PTS * 3;
        const float* F = flow + (size_t)b * N_PTS * 3;

        float mx[8], my[8], mz[8], p2[8], gr[8];
        unsigned thr[8], o[8][4];
        #pragma unroll
        for (int r = 0; r < 8; ++r) {
            int i = i0w + r;
            float px = P[i*3+0], py = P[i*3+1], pz = P[i*3+2];
            mx[r] = -2.0f * px; my[r] = -2.0f * py; mz[r] = -2.0f * pz;
            p2[r] = fmaf(px, px, fmaf(py, py, pz * pz));
            gr[r] = __builtin_inff();
            thr[r] = 0xFFFFFFFFu;
            #pragma unroll
            for (int k = 0; k < 4; ++k) o[r][k] = 0xFFFFFFFFu;
        }

        // tight-but-cheap thr: per-32-half top-4 via 5-stage butterfly,
        // bound = max of the two halves' 4th keys (8 distinct real keys >= true 8th)
        auto update_thr = [&]() {
            #pragma unroll
            for (int r = 0; r < 8; ++r) {
                unsigned m0 = o[r][0], m1 = o[r][1], m2 = o[r][2], m3 = o[r][3];
                #pragma unroll
                for (int d = 1; d <= 16; d <<= 1) {
                    unsigned q0 = (unsigned)__shfl_xor((int)m0, d, 64);
                    unsigned q1 = (unsigned)__shfl_xor((int)m1, d, 64);
                    unsigned q2 = (unsigned)__shfl_xor((int)m2, d, 64);
                    unsigned q3 = (unsigned)__shfl_xor((int)m3, d, 64);
                    unsigned c0 = min(m0, q3), c1 = min(m1, q2);
                    unsigned c2 = min(m2, q1), c3 = min(m3, q0);
                    ce(c0, c2); ce(c1, c3); ce(c0, c1); ce(c2, c3);
                    m0 = c0; m1 = c1; m2 = c2; m3 = c3;
                }
                unsigned bound = max(m3, (unsigned)__shfl_xor((int)m3, 32, 64));
                thr[r] = min(thr[r], bound);
                // +2 truncation-buckets slack: float gate passes superset of key<=thr
                float thr_up = __uint_as_float((thr[r] & 0xFFFFE000u) + 0x4000u);
                gr[r] = thr_up - p2[r];
            }
        };

        auto gated_span = [&](int t0, int st0, int st1) {
            #pragma unroll 2
            for (int st = st0; st < st1; ++st) {
                float4 qa = sq[st * 64 + lane];
                int j = t0 + st * 64 + lane;
                float s[8];
                #pragma unroll
                for (int r = 0; r < 8; ++r)
                    s[r] = fmaf(mx[r], qa.x, fmaf(my[r], qa.y, fmaf(mz[r], qa.z, qa.w)));
                #pragma unroll
                for (int r = 0; r < 8; ++r) {
                    if (__any(s[r] <= gr[r])) {
                        float d2 = fmaxf(s[r] + p2[r], 0.0f);
                        unsigned key = (__float_as_uint(d2) & 0xFFFFE000u) | (unsigned)j;
                        key = (j == i0w + r) ? 0xFFFFFFFFu : key;
                        insert4(o[r], key);
                    }
                }
            }
        };

        #pragma unroll 1
        for (int tile = 0; tile < N_PTS / STILE; ++tile) {   // 4 tiles
            const int t0 = tile * STILE;
            __syncthreads();
            #pragma unroll
            for (int u = tid; u < STILE; u += 256) {
                int g = t0 + u;
                float qx = P[g*3+0], qy = P[g*3+1], qz = P[g*3+2];
                sq[u] = make_float4(qx, qy, qz, fmaf(qx, qx, fmaf(qy, qy, qz * qz)));
            }
            __syncthreads();

            if (tile == 0) {
                // phase A: first 1024 cands unconditional (sample)
                #pragma unroll 4
                for (int st = 0; st < 16; ++st) {
                    float4 qa = sq[st * 64 + lane];
                    int j = st * 64 + lane;
                    #pragma unroll
                    for (int r = 0; r < 8; ++r) {
                        float ss = fmaf(mx[r], qa.x, fmaf(my[r], qa.y, fmaf(mz[r], qa.z, qa.w)));
                        float d2 = fmaxf(ss + p2[r], 0.0f);
                        unsigned key = (__float_as_uint(d2) & 0xFFFFE000u) | (unsigned)j;
                        key = (j == i0w + r) ? 0xFFFFFFFFu : key;
                        insert4(o[r], key);
                    }
                }
                update_thr();
                gated_span(0, 16, 32);     // rest of tile 0 gated
            } else {
                gated_span(t0, 0, 32);
                if (tile == 1) update_thr();
            }
        }

        // final per-point top-8 + epilogue (lane = (point, k) pair)
        const int pr = lane >> 3, kk = lane & 7;
        unsigned mykey = 0xFFFFFFFFu;
        #pragma unroll
        for (int r = 0; r < 8; ++r) {
            unsigned m[8] = {o[r][0], o[r][1], o[r][2], o[r][3],
                             0xFFFFFFFFu, 0xFFFFFFFFu, 0xFFFFFFFFu, 0xFFFFFFFFu};
            merge64(m);
            if (pr == r) {
                unsigned k2 = m[0];
                #pragma unroll
                for (int t = 1; t < 8; ++t) k2 = (kk == t) ? m[t] : k2;
                mykey = k2;
            }
        }
        const int i = i0w + pr;
        const int j = (int)(mykey & (N_PTS - 1));
        float dx = F[i*3+0] - F[j*3+0];
        float dy = F[i*3+1] - F[j*3+1];
        float dz = F[i*3+2] - F[j*3+2];
        float sv = sqrtf(fmaf(dx, dx, fmaf(dy, dy, dz * dz)));
        #pragma unroll
        for (int d = 1; d < 64; d <<= 1) sv += __shfl_xor(sv, d, 64);
        if (lane == 0) psum[wv] = sv;
        __syncthreads();
        if (tid == 0) {
            // W_SMOOTH(0.5) / (B*N*K); each lane contributed exactly one (pt,k)
            atomicAdd(out, (psum[0] + psum[1] + psum[2] + psum[3]) *
                           (0.5f / ((float)BATCH * N_PTS * KNN)));
        }
    } else {
        // ================= chamfer role: block owns 256 rows, full scan =================
        const int cb = bx - SM_BLOCKS;        // 0..127
        const int z  = cb >> 5;               // combo: b + 2*dir
        const int rb = cb & 31;
        const int b = z & 1, dir = z >> 1;
        const float* P1 = pc1  + (size_t)b * N_PTS * 3;
        const float* P2 = pc2  + (size_t)b * N_PTS * 3;
        const float* FL = flow + (size_t)b * N_PTS * 3;
        const int wv = tid >> 6, lane = tid & 63;
        const int rw = tid >> 1, sub = tid & 1;
        const int r0 = rb * CH_ROWS + rw * 2;     // rows r0, r0+1

        float mx0, my0, mz0, p20, mx1, my1, mz1, p21;
        {
            float px, py, pz;
            if (dir == 0) {
                px = P1[r0*3+0] + FL[r0*3+0];
                py = P1[r0*3+1] + FL[r0*3+1];
                pz = P1[r0*3+2] + FL[r0*3+2];
            } else {
                px = P2[r0*3+0]; py = P2[r0*3+1]; pz = P2[r0*3+2];
            }
            mx0 = -2.0f * px; my0 = -2.0f * py; mz0 = -2.0f * pz;
            p20 = fmaf(px, px, fmaf(py, py, pz * pz));
            int r1 = r0 + 1;
            if (dir == 0) {
                px = P1[r1*3+0] + FL[r1*3+0];
                py = P1[r1*3+1] + FL[r1*3+1];
                pz = P1[r1*3+2] + FL[r1*3+2];
            } else {
                px = P2[r1*3+0]; py = P2[r1*3+1]; pz = P2[r1*3+2];
            }
            mx1 = -2.0f * px; my1 = -2.0f * py; mz1 = -2.0f * pz;
            p21 = fmaf(px, px, fmaf(py, py, pz * pz));
        }
        float b0 = __builtin_inff(), b1 = __builtin_inff();

        #pragma unroll 1
        for (int tile = 0; tile < N_PTS / STILE; ++tile) {
            const int t0 = tile * STILE;
            __syncthreads();
            #pragma unroll
            for (int u = tid; u < STILE; u += 256) {
                int g = t0 + u;
                float qx, qy, qz;
                if (dir == 0) {
                    qx = P2[g*3+0]; qy = P2[g*3+1]; qz = P2[g*3+2];
                } else {
                    qx = P1[g*3+0] + FL[g*3+0];
                    qy = P1[g*3+1] + FL[g*3+1];
                    qz = P1[g*3+2] + FL[g*3+2];
                }
                sq[u] = make_float4(qx, qy, qz, fmaf(qx, qx, fmaf(qy, qy, qz * qz)));
            }
            __syncthreads();

            const float4* base = sq + sub * (STILE / 2);
            #pragma unroll 8
            for (int c = 0; c < STILE / 2; ++c) {
                float4 q = base[c];
                float s0 = fmaf(mx0, q.x, fmaf(my0, q.y, fmaf(mz0, q.z, q.w)));
                float s1 = fmaf(mx1, q.x, fmaf(my1, q.y, fmaf(mz1, q.z, q.w)));
                b0 = fminf(b0, s0);
                b1 = fminf(b1, s1);
            }
        }

        // merge the two cand-subs, sqrt, block-sum, one atomicAdd
        b0 = fminf(b0, __shfl_xor(b0, 1, 64));
        b1 = fminf(b1, __shfl_xor(b1, 1, 64));
        float val = (sub == 0)
            ? (sqrtf(fmaxf(b0 + p20, 0.0f)) + sqrtf(fmaxf(b1 + p21, 0.0f)))
            : 0.0f;
        #pragma unroll
        for (int d = 1; d < 64; d <<= 1) val += __shfl_xor(val, d, 64);
        if (lane == 0) psum[wv] = val;
        __syncthreads();
        if (tid == 0) {
            atomicAdd(out, (psum[0] + psum[1] + psum[2] + psum[3]) *
                           (1.0f / ((float)BATCH * N_PTS)));
        }
    }
}

extern "C" void kernel_launch(void* const* d_in, const int* in_sizes, int n_in,
                              void* d_out, int out_size, void* d_ws, size_t ws_size,
                              hipStream_t stream) {
    const float* pc1  = (const float*)d_in[0];
    const float* pc2  = (const float*)d_in[1];
    const float* flow = (const float*)d_in[2];
    float* out = (float*)d_out;

    hipMemsetAsync(out, 0, sizeof(float), stream);
    mega_kernel<<<dim3(SM_BLOCKS + CH_BLOCKS), 256, 0, stream>>>(pc1, pc2, flow, out);
}

// Round 10
// 143.799 us; speedup vs baseline: 1.1521x; 1.1521x over previous
//
#include <hip/hip_runtime.h>

#define N_PTS 8192
#define BATCH 2
#define KNN 8
#define STILE 2048                       // smooth LDS tile (points)
#define SM_PPB 16                        // smooth points per block (4 waves x 4)
#define SM_BLOCKS (BATCH * N_PTS / SM_PPB)    // 1024
#define CH_SLICE 1024                    // chamfer candidates per block
#define CH_R 8                           // chamfer rows per thread
#define CH_ROWG (256 * CH_R)             // 2048 rows per block
#define NSLICE (N_PTS / CH_SLICE)        // 8
#define NROWG (N_PTS / CH_ROWG)          // 4
#define CH_BLOCKS (4 * NSLICE * NROWG)   // 128
// ws layout (floats): part[4][NSLICE][N_PTS] = 1 MiB, then smsum[SM_BLOCKS]
#define OFF_SMSUM (4 * NSLICE * N_PTS)

// ---------------- helpers ----------------
__device__ __forceinline__ void ce(unsigned &x, unsigned &y) {
    unsigned lo = min(x, y), hi = max(x, y); x = lo; y = hi;
}

__device__ __forceinline__ void insert4(unsigned o[4], unsigned key) {
    unsigned n0 = min(o[0], key);
    unsigned n1 = max(o[0], min(o[1], key));
    unsigned n2 = max(o[1], min(o[2], key));
    unsigned n3 = max(o[2], min(o[3], key));
    o[0]=n0; o[1]=n1; o[2]=n2; o[3]=n3;
}

__device__ __forceinline__ void merge_stage8(unsigned m[8], int d) {
    unsigned p[8], c[8];
    #pragma unroll
    for (int k = 0; k < 8; ++k) p[k] = (unsigned)__shfl_xor((int)m[k], d, 64);
    #pragma unroll
    for (int k = 0; k < 8; ++k) c[k] = min(m[k], p[7-k]);
    ce(c[0],c[4]); ce(c[1],c[5]); ce(c[2],c[6]); ce(c[3],c[7]);
    ce(c[0],c[2]); ce(c[1],c[3]); ce(c[4],c[6]); ce(c[5],c[7]);
    ce(c[0],c[1]); ce(c[2],c[3]); ce(c[4],c[5]); ce(c[6],c[7]);
    #pragma unroll
    for (int k = 0; k < 8; ++k) m[k] = c[k];
}

__device__ __forceinline__ void merge64(unsigned m[8]) {
    merge_stage8(m, 1); merge_stage8(m, 2); merge_stage8(m, 4);
    merge_stage8(m, 8); merge_stage8(m, 16); merge_stage8(m, 32);
}

// ---------------- mega: 128 chamfer blocks first, then 1024 smooth blocks ----------------
__global__ __launch_bounds__(256, 4) void mega_kernel(
        const float* __restrict__ pc1, const float* __restrict__ pc2,
        const float* __restrict__ flow, float* __restrict__ part,
        float* __restrict__ smsum) {
    __shared__ float4 sq[STILE];   // 32 KiB
    __shared__ float psum[4];
    const int tid = threadIdx.x;
    const int bx = blockIdx.x;

    if (bx < CH_BLOCKS) {
        // ===== chamfer role: 2048 rows x 1024-cand slice, broadcast reads =====
        const int z     = bx >> 5;           // combo: b + 2*dir
        const int rowg  = bx & 3;
        const int slice = (bx >> 2) & 7;
        const int b = z & 1, dir = z >> 1;
        const float* P1 = pc1  + (size_t)b * N_PTS * 3;
        const float* P2 = pc2  + (size_t)b * N_PTS * 3;
        const float* FL = flow + (size_t)b * N_PTS * 3;
        const int m0 = slice * CH_SLICE;

        // stage 1024 cands: raw xyz into sraw (12 KiB at sq[1024..]), then (x,y,z,|q|^2)
        float* sraw = (float*)(sq + CH_SLICE);
        #pragma unroll
        for (int u = tid; u < CH_SLICE * 3 / 4; u += 256) {   // 768 float4
            float4 v;
            if (dir == 0) {
                v = ((const float4*)(P2 + (size_t)m0 * 3))[u];
            } else {
                float4 a = ((const float4*)(P1 + (size_t)m0 * 3))[u];
                float4 f = ((const float4*)(FL + (size_t)m0 * 3))[u];
                v = make_float4(a.x + f.x, a.y + f.y, a.z + f.z, a.w + f.w);
            }
            ((float4*)sraw)[u] = v;
        }

        const int i0 = rowg * CH_ROWG + tid * CH_R;
        float mx[CH_R], my_[CH_R], mz_[CH_R], p2[CH_R], best[CH_R];
        #pragma unroll
        for (int r = 0; r < CH_R; ++r) {
            int row = i0 + r;
            float px, py, pz;
            if (dir == 0) {
                px = P1[row*3+0] + FL[row*3+0];
                py = P1[row*3+1] + FL[row*3+1];
                pz = P1[row*3+2] + FL[row*3+2];
            } else {
                px = P2[row*3+0]; py = P2[row*3+1]; pz = P2[row*3+2];
            }
            mx[r] = -2.0f * px; my_[r] = -2.0f * py; mz_[r] = -2.0f * pz;
            p2[r] = fmaf(px, px, fmaf(py, py, pz * pz));
            best[r] = __builtin_inff();
        }
        __syncthreads();
        #pragma unroll
        for (int u = tid; u < CH_SLICE; u += 256) {
            float qx = sraw[u*3+0], qy = sraw[u*3+1], qz = sraw[u*3+2];
            sq[u] = make_float4(qx, qy, qz, fmaf(qx, qx, fmaf(qy, qy, qz * qz)));
        }
        __syncthreads();

        #pragma unroll 8
        for (int jj = 0; jj < CH_SLICE; ++jj) {
            float4 q = sq[jj];   // wave-uniform broadcast: conflict-free
            #pragma unroll
            for (int r = 0; r < CH_R; ++r) {
                float s = fmaf(mx[r], q.x, fmaf(my_[r], q.y, fmaf(mz_[r], q.z, q.w)));
                best[r] = fminf(best[r], s);
            }
        }

        float* dst = part + ((size_t)(z * NSLICE + slice)) * N_PTS + i0;
        *(float4*)(dst)     = make_float4(fmaxf(best[0]+p2[0],0.f), fmaxf(best[1]+p2[1],0.f),
                                          fmaxf(best[2]+p2[2],0.f), fmaxf(best[3]+p2[3],0.f));
        *(float4*)(dst + 4) = make_float4(fmaxf(best[4]+p2[4],0.f), fmaxf(best[5]+p2[5],0.f),
                                          fmaxf(best[6]+p2[6],0.f), fmaxf(best[7]+p2[7],0.f));
    } else {
        // ===== smooth role: wave owns 4 points, lane owns candidate slice =====
        const int s  = bx - CH_BLOCKS;        // 0..1023
        const int b  = s >> 9;
        const int sx = s & 511;
        const int wv = tid >> 6, lane = tid & 63;
        const int i0w = sx * SM_PPB + wv * 4;
        const float* P = pc1  + (size_t)b * N_PTS * 3;
        const float* F = flow + (size_t)b * N_PTS * 3;

        float mx[4], my[4], mz[4], p2[4], gr[4];
        unsigned thr[4], o[4][4];
        #pragma unroll
        for (int r = 0; r < 4; ++r) {
            int i = i0w + r;
            float px = P[i*3+0], py = P[i*3+1], pz = P[i*3+2];
            mx[r] = -2.0f * px; my[r] = -2.0f * py; mz[r] = -2.0f * pz;
            p2[r] = fmaf(px, px, fmaf(py, py, pz * pz));
            gr[r] = __builtin_inff();
            thr[r] = 0xFFFFFFFFu;
            #pragma unroll
            for (int k = 0; k < 4; ++k) o[r][k] = 0xFFFFFFFFu;
        }

        // tight thr: per-32-half true top-4 via 5-stage butterfly;
        // bound = max of the two halves' 4th keys (8 distinct real keys >= true 8th)
        auto update_thr = [&]() {
            #pragma unroll
            for (int r = 0; r < 4; ++r) {
                unsigned m0 = o[r][0], m1 = o[r][1], m2 = o[r][2], m3 = o[r][3];
                #pragma unroll
                for (int d = 1; d <= 16; d <<= 1) {
                    unsigned q0 = (unsigned)__shfl_xor((int)m0, d, 64);
                    unsigned q1 = (unsigned)__shfl_xor((int)m1, d, 64);
                    unsigned q2 = (unsigned)__shfl_xor((int)m2, d, 64);
                    unsigned q3 = (unsigned)__shfl_xor((int)m3, d, 64);
                    unsigned c0 = min(m0, q3), c1 = min(m1, q2);
                    unsigned c2 = min(m2, q1), c3 = min(m3, q0);
                    ce(c0, c2); ce(c1, c3); ce(c0, c1); ce(c2, c3);
                    m0 = c0; m1 = c1; m2 = c2; m3 = c3;
                }
                unsigned bound = max(m3, (unsigned)__shfl_xor((int)m3, 32, 64));
                thr[r] = min(thr[r], bound);
                // +2 truncation-buckets slack: gate passes superset of key<=thr
                float thr_up = __uint_as_float((thr[r] & 0xFFFFE000u) + 0x4000u);
                gr[r] = thr_up - p2[r];
            }
        };

        auto gated_span = [&](int t0, int st0, int st1) {
            #pragma unroll 2
            for (int st = st0; st < st1; ++st) {
                float4 qa = sq[st * 64 + lane];
                int j = t0 + st * 64 + lane;
                float sc[4];
                #pragma unroll
                for (int r = 0; r < 4; ++r)
                    sc[r] = fmaf(mx[r], qa.x, fmaf(my[r], qa.y, fmaf(mz[r], qa.z, qa.w)));
                #pragma unroll
                for (int r = 0; r < 4; ++r) {
                    if (__any(sc[r] <= gr[r])) {
                        float d2 = fmaxf(sc[r] + p2[r], 0.0f);
                        unsigned key = (__float_as_uint(d2) & 0xFFFFE000u) | (unsigned)j;
                        key = (j == i0w + r) ? 0xFFFFFFFFu : key;
                        insert4(o[r], key);
                    }
                }
            }
        };

        #pragma unroll 1
        for (int tile = 0; tile < N_PTS / STILE; ++tile) {   // 4 tiles
            const int t0 = tile * STILE;
            __syncthreads();
            #pragma unroll
            for (int u = tid; u < STILE; u += 256) {
                int g = t0 + u;
                float qx = P[g*3+0], qy = P[g*3+1], qz = P[g*3+2];
                sq[u] = make_float4(qx, qy, qz, fmaf(qx, qx, fmaf(qy, qy, qz * qz)));
            }
            __syncthreads();

            if (tile == 0) {
                // sample: first 1024 cands unconditional
                #pragma unroll 4
                for (int st = 0; st < 16; ++st) {
                    float4 qa = sq[st * 64 + lane];
                    int j = st * 64 + lane;
                    #pragma unroll
                    for (int r = 0; r < 4; ++r) {
                        float ss = fmaf(mx[r], qa.x, fmaf(my[r], qa.y, fmaf(mz[r], qa.z, qa.w)));
                        float d2 = fmaxf(ss + p2[r], 0.0f);
                        unsigned key = (__float_as_uint(d2) & 0xFFFFE000u) | (unsigned)j;
                        key = (j == i0w + r) ? 0xFFFFFFFFu : key;
                        insert4(o[r], key);
                    }
                }
                update_thr();
                gated_span(0, 16, 32);
                update_thr();
            } else {
                gated_span(t0, 0, 32);
                if (tile <= 2) update_thr();
            }
        }

        // final per-point top-8 + epilogue (sel = (point, k); halves duplicate x2)
        unsigned fin[4][8];
        #pragma unroll
        for (int r = 0; r < 4; ++r) {
            unsigned m[8] = {o[r][0], o[r][1], o[r][2], o[r][3],
                             0xFFFFFFFFu, 0xFFFFFFFFu, 0xFFFFFFFFu, 0xFFFFFFFFu};
            merge64(m);
            #pragma unroll
            for (int k = 0; k < 8; ++k) fin[r][k] = m[k];
        }
        const int sel = lane & 31;
        unsigned key = fin[0][0];
        #pragma unroll
        for (int rr = 0; rr < 4; ++rr)
            #pragma unroll
            for (int kk = 0; kk < 8; ++kk)
                if (sel == rr * 8 + kk) key = fin[rr][kk];
        const int r = sel >> 3;
        const int i = i0w + r;
        const int j = (int)(key & (N_PTS - 1));
        float dx = F[i*3+0] - F[j*3+0];
        float dy = F[i*3+1] - F[j*3+1];
        float dz = F[i*3+2] - F[j*3+2];
        float sv = sqrtf(fmaf(dx, dx, fmaf(dy, dy, dz * dz)));
        #pragma unroll
        for (int d = 1; d < 64; d <<= 1) sv += __shfl_xor(sv, d, 64);
        if (lane == 0) psum[wv] = sv;
        __syncthreads();
        if (tid == 0)
            smsum[s] = psum[0] + psum[1] + psum[2] + psum[3];  // raw, x2-counted
    }
}

// ---------------- finish: single block, sole writer of out ----------------
__global__ __launch_bounds__(1024) void finish_kernel(const float* __restrict__ part,
                                                      const float* __restrict__ smsum,
                                                      float* __restrict__ out) {
    const int t = threadIdx.x;
    float ch = 0.0f;
    #pragma unroll 1
    for (int z = 0; z < 4; ++z) {
        #pragma unroll 2
        for (int g = 0; g < 8; ++g) {
            int row = g * 1024 + t;
            const float* p = part + (size_t)z * NSLICE * N_PTS + row;
            float v = p[0];
            #pragma unroll
            for (int s = 1; s < NSLICE; ++s) v = fminf(v, p[(size_t)s * N_PTS]);
            ch += sqrtf(v);
        }
    }
    float local = ch * (1.0f / (float)(BATCH * N_PTS))
                + smsum[t] * (0.25f / ((float)BATCH * N_PTS * KNN));
    #pragma unroll
    for (int d = 1; d < 64; d <<= 1) local += __shfl_xor(local, d, 64);
    __shared__ float wsum[16];
    if ((t & 63) == 0) wsum[t >> 6] = local;
    __syncthreads();
    if (t == 0) {
        float tot = 0.0f;
        #pragma unroll
        for (int k = 0; k < 16; ++k) tot += wsum[k];
        out[0] = tot;
    }
}

extern "C" void kernel_launch(void* const* d_in, const int* in_sizes, int n_in,
                              void* d_out, int out_size, void* d_ws, size_t ws_size,
                              hipStream_t stream) {
    const float* pc1  = (const float*)d_in[0];
    const float* pc2  = (const float*)d_in[1];
    const float* flow = (const float*)d_in[2];
    float* out = (float*)d_out;
    float* part  = (float*)d_ws;                 // 1 MiB
    float* smsum = (float*)d_ws + OFF_SMSUM;     // 4 KiB

    mega_kernel<<<dim3(CH_BLOCKS + SM_BLOCKS), 256, 0, stream>>>(pc1, pc2, flow, part, smsum);
    finish_kernel<<<dim3(1), 1024, 0, stream>>>(part, smsum, out);
}

// Round 12
// 138.288 us; speedup vs baseline: 1.1980x; 1.0399x over previous
//
#include <hip/hip_runtime.h>

#define N_PTS 8192
#define BATCH 2
#define KNN 8
#define STILE 2048                          // LDS tile (points), 32 KiB
#define SM_PPB 16                           // smooth points per block (4 waves x 4)
#define SM_BLOCKS (BATCH * N_PTS / SM_PPB)  // 1024
#define CH_BLOCKS 512                       // 4 combos x 128 row-blocks (64 rows)
#define NBLOCKS (CH_BLOCKS + SM_BLOCKS)     // 1536
// ws layout (floats): chsum[512], smsum[1024] = 6 KiB
#define OFF_SMSUM 512

// ---------------- helpers ----------------
__device__ __forceinline__ void ce(unsigned &x, unsigned &y) {
    unsigned lo = min(x, y), hi = max(x, y); x = lo; y = hi;
}

__device__ __forceinline__ void insert4(unsigned o[4], unsigned key) {
    unsigned n0 = min(o[0], key);
    unsigned n1 = max(o[0], min(o[1], key));
    unsigned n2 = max(o[1], min(o[2], key));
    unsigned n3 = max(o[2], min(o[3], key));
    o[0]=n0; o[1]=n1; o[2]=n2; o[3]=n3;
}

__device__ __forceinline__ void merge_stage8(unsigned m[8], int d) {
    unsigned p[8], c[8];
    #pragma unroll
    for (int k = 0; k < 8; ++k) p[k] = (unsigned)__shfl_xor((int)m[k], d, 64);
    #pragma unroll
    for (int k = 0; k < 8; ++k) c[k] = min(m[k], p[7-k]);
    ce(c[0],c[4]); ce(c[1],c[5]); ce(c[2],c[6]); ce(c[3],c[7]);
    ce(c[0],c[2]); ce(c[1],c[3]); ce(c[4],c[6]); ce(c[5],c[7]);
    ce(c[0],c[1]); ce(c[2],c[3]); ce(c[4],c[5]); ce(c[6],c[7]);
    #pragma unroll
    for (int k = 0; k < 8; ++k) m[k] = c[k];
}

__device__ __forceinline__ void merge64(unsigned m[8]) {
    merge_stage8(m, 1); merge_stage8(m, 2); merge_stage8(m, 4);
    merge_stage8(m, 8); merge_stage8(m, 16); merge_stage8(m, 32);
}

// ---------------- mega: 512 chamfer full-scan blocks + 1024 smooth blocks ----------------
__global__ __launch_bounds__(256, 4) void mega_kernel(
        const float* __restrict__ pc1, const float* __restrict__ pc2,
        const float* __restrict__ flow, float* __restrict__ chsum,
        float* __restrict__ smsum) {
    __shared__ float4 sq[STILE];   // 32 KiB
    __shared__ float psum[4];
    const int tid = threadIdx.x;
    const int bx = blockIdx.x;

    if (bx < CH_BLOCKS) {
        // ===== chamfer role: 64 rows, full 8192-cand scan, one float out =====
        const int z  = bx >> 7;              // combo: b + 2*dir
        const int rb = bx & 127;             // 64-row block
        const int b = z & 1, dir = z >> 1;
        const float* P1 = pc1  + (size_t)b * N_PTS * 3;
        const float* P2 = pc2  + (size_t)b * N_PTS * 3;
        const float* FL = flow + (size_t)b * N_PTS * 3;
        const int wv = tid >> 6, lane = tid & 63;
        const int sub = tid & 7;             // candidate sub-slice
        const int r0 = rb * 64 + 2 * (tid >> 3);   // rows r0, r0+1

        float mx0, my0, mz0, p20, mx1, my1, mz1, p21;
        {
            float px, py, pz;
            if (dir == 0) {
                px = P1[r0*3+0] + FL[r0*3+0];
                py = P1[r0*3+1] + FL[r0*3+1];
                pz = P1[r0*3+2] + FL[r0*3+2];
            } else {
                px = P2[r0*3+0]; py = P2[r0*3+1]; pz = P2[r0*3+2];
            }
            mx0 = -2.0f * px; my0 = -2.0f * py; mz0 = -2.0f * pz;
            p20 = fmaf(px, px, fmaf(py, py, pz * pz));
            int r1 = r0 + 1;
            if (dir == 0) {
                px = P1[r1*3+0] + FL[r1*3+0];
                py = P1[r1*3+1] + FL[r1*3+1];
                pz = P1[r1*3+2] + FL[r1*3+2];
            } else {
                px = P2[r1*3+0]; py = P2[r1*3+1]; pz = P2[r1*3+2];
            }
            mx1 = -2.0f * px; my1 = -2.0f * py; mz1 = -2.0f * pz;
            p21 = fmaf(px, px, fmaf(py, py, pz * pz));
        }
        float b0 = __builtin_inff(), b1 = __builtin_inff();

        #pragma unroll 1
        for (int tile = 0; tile < N_PTS / STILE; ++tile) {   // 4 tiles
            const int t0 = tile * STILE;
            __syncthreads();
            #pragma unroll
            for (int u = tid; u < STILE; u += 256) {
                int g = t0 + u;
                float qx, qy, qz;
                if (dir == 0) {
                    qx = P2[g*3+0]; qy = P2[g*3+1]; qz = P2[g*3+2];
                } else {
                    qx = P1[g*3+0] + FL[g*3+0];
                    qy = P1[g*3+1] + FL[g*3+1];
                    qz = P1[g*3+2] + FL[g*3+2];
                }
                sq[u] = make_float4(qx, qy, qz, fmaf(qx, qx, fmaf(qy, qy, qz * qz)));
            }
            __syncthreads();

            // sub scans sq[c*8+sub]: 8 consecutive float4/wave-step = 32 banks once,
            // 8 lanes broadcast each address -> conflict-free, 16 VALU per ds_read
            #pragma unroll 8
            for (int c = 0; c < STILE / 8; ++c) {
                float4 q = sq[c * 8 + sub];
                float s0 = fmaf(mx0, q.x, fmaf(my0, q.y, fmaf(mz0, q.z, q.w)));
                float s1 = fmaf(mx1, q.x, fmaf(my1, q.y, fmaf(mz1, q.z, q.w)));
                b0 = fminf(b0, s0);
                b1 = fminf(b1, s1);
            }
        }

        // merge the 8 subs (wave-local: xor bits 0..2), sqrt, block-sum
        #pragma unroll
        for (int d = 1; d <= 4; d <<= 1) {
            b0 = fminf(b0, __shfl_xor(b0, d, 64));
            b1 = fminf(b1, __shfl_xor(b1, d, 64));
        }
        float val = (sub == 0)
            ? (sqrtf(fmaxf(b0 + p20, 0.0f)) + sqrtf(fmaxf(b1 + p21, 0.0f)))
            : 0.0f;
        #pragma unroll
        for (int d = 1; d < 64; d <<= 1) val += __shfl_xor(val, d, 64);
        if (lane == 0) psum[wv] = val;
        __syncthreads();
        if (tid == 0) chsum[bx] = psum[0] + psum[1] + psum[2] + psum[3];
    } else {
        // ===== smooth role: wave owns 4 points, lane owns candidate slice =====
        const int s  = bx - CH_BLOCKS;        // 0..1023
        const int b  = s >> 9;
        const int sx = s & 511;
        const int wv = tid >> 6, lane = tid & 63;
        const int i0w = sx * SM_PPB + wv * 4;
        const float* P = pc1  + (size_t)b * N_PTS * 3;
        const float* F = flow + (size_t)b * N_PTS * 3;

        float mx[4], my[4], mz[4], p2[4], gr[4];
        unsigned thr[4], o[4][4];
        #pragma unroll
        for (int r = 0; r < 4; ++r) {
            int i = i0w + r;
            float px = P[i*3+0], py = P[i*3+1], pz = P[i*3+2];
            mx[r] = -2.0f * px; my[r] = -2.0f * py; mz[r] = -2.0f * pz;
            p2[r] = fmaf(px, px, fmaf(py, py, pz * pz));
            gr[r] = __builtin_inff();
            thr[r] = 0xFFFFFFFFu;
            #pragma unroll
            for (int k = 0; k < 4; ++k) o[r][k] = 0xFFFFFFFFu;
        }

        // tight thr: per-32-half true top-4 via 5-stage butterfly;
        // bound = max of the two halves' 4th keys (8 distinct real keys >= true 8th)
        auto update_thr = [&]() {
            #pragma unroll
            for (int r = 0; r < 4; ++r) {
                unsigned m0 = o[r][0], m1 = o[r][1], m2 = o[r][2], m3 = o[r][3];
                #pragma unroll
                for (int d = 1; d <= 16; d <<= 1) {
                    unsigned q0 = (unsigned)__shfl_xor((int)m0, d, 64);
                    unsigned q1 = (unsigned)__shfl_xor((int)m1, d, 64);
                    unsigned q2 = (unsigned)__shfl_xor((int)m2, d, 64);
                    unsigned q3 = (unsigned)__shfl_xor((int)m3, d, 64);
                    unsigned c0 = min(m0, q3), c1 = min(m1, q2);
                    unsigned c2 = min(m2, q1), c3 = min(m3, q0);
                    ce(c0, c2); ce(c1, c3); ce(c0, c1); ce(c2, c3);
                    m0 = c0; m1 = c1; m2 = c2; m3 = c3;
                }
                unsigned bound = max(m3, (unsigned)__shfl_xor((int)m3, 32, 64));
                thr[r] = min(thr[r], bound);
                // +2 truncation-buckets slack: gate passes superset of key<=thr
                float thr_up = __uint_as_float((thr[r] & 0xFFFFE000u) + 0x4000u);
                gr[r] = thr_up - p2[r];
            }
        };

        auto gated_span = [&](int t0, int st0, int st1) {
            #pragma unroll 2
            for (int st = st0; st < st1; ++st) {
                float4 qa = sq[st * 64 + lane];
                int j = t0 + st * 64 + lane;
                float sc[4];
                #pragma unroll
                for (int r = 0; r < 4; ++r)
                    sc[r] = fmaf(mx[r], qa.x, fmaf(my[r], qa.y, fmaf(mz[r], qa.z, qa.w)));
                #pragma unroll
                for (int r = 0; r < 4; ++r) {
                    if (__any(sc[r] <= gr[r])) {
                        float d2 = fmaxf(sc[r] + p2[r], 0.0f);
                        unsigned key = (__float_as_uint(d2) & 0xFFFFE000u) | (unsigned)j;
                        key = (j == i0w + r) ? 0xFFFFFFFFu : key;
                        insert4(o[r], key);
                    }
                }
            }
        };

        #pragma unroll 1
        for (int tile = 0; tile < N_PTS / STILE; ++tile) {   // 4 tiles
            const int t0 = tile * STILE;
            __syncthreads();
            #pragma unroll
            for (int u = tid; u < STILE; u += 256) {
                int g = t0 + u;
                float qx = P[g*3+0], qy = P[g*3+1], qz = P[g*3+2];
                sq[u] = make_float4(qx, qy, qz, fmaf(qx, qx, fmaf(qy, qy, qz * qz)));
            }
            __syncthreads();

            if (tile == 0) {
                // sample: first 1024 cands unconditional
                #pragma unroll 4
                for (int st = 0; st < 16; ++st) {
                    float4 qa = sq[st * 64 + lane];
                    int j = st * 64 + lane;
                    #pragma unroll
                    for (int r = 0; r < 4; ++r) {
                        float ss = fmaf(mx[r], qa.x, fmaf(my[r], qa.y, fmaf(mz[r], qa.z, qa.w)));
                        float d2 = fmaxf(ss + p2[r], 0.0f);
                        unsigned key = (__float_as_uint(d2) & 0xFFFFE000u) | (unsigned)j;
                        key = (j == i0w + r) ? 0xFFFFFFFFu : key;
                        insert4(o[r], key);
                    }
                }
                update_thr();
                gated_span(0, 16, 32);
                update_thr();
            } else {
                gated_span(t0, 0, 32);
                if (tile <= 2) update_thr();
            }
        }

        // final per-point top-8 + epilogue (sel = (point, k); halves duplicate x2)
        unsigned fin[4][8];
        #pragma unroll
        for (int r = 0; r < 4; ++r) {
            unsigned m[8] = {o[r][0], o[r][1], o[r][2], o[r][3],
                             0xFFFFFFFFu, 0xFFFFFFFFu, 0xFFFFFFFFu, 0xFFFFFFFFu};
            merge64(m);
            #pragma unroll
            for (int k = 0; k < 8; ++k) fin[r][k] = m[k];
        }
        const int sel = lane & 31;
        unsigned key = fin[0][0];
        #pragma unroll
        for (int rr = 0; rr < 4; ++rr)
            #pragma unroll
            for (int kk = 0; kk < 8; ++kk)
                if (sel == rr * 8 + kk) key = fin[rr][kk];
        const int r = sel >> 3;
        const int i = i0w + r;
        const int j = (int)(key & (N_PTS - 1));
        float dx = F[i*3+0] - F[j*3+0];
        float dy = F[i*3+1] - F[j*3+1];
        float dz = F[i*3+2] - F[j*3+2];
        float sv = sqrtf(fmaf(dx, dx, fmaf(dy, dy, dz * dz)));
        #pragma unroll
        for (int d = 1; d < 64; d <<= 1) sv += __shfl_xor(sv, d, 64);
        if (lane == 0) psum[wv] = sv;
        __syncthreads();
        if (tid == 0)
            smsum[s] = psum[0] + psum[1] + psum[2] + psum[3];  // raw, x2-counted
    }
}

// ---------------- finish: single block reads 6 KiB, sole writer of out ----------------
__global__ __launch_bounds__(512) void finish_kernel(const float* __restrict__ chsum,
                                                     const float* __restrict__ smsum,
                                                     float* __restrict__ out) {
    const int t = threadIdx.x;
    float ch = chsum[t];                       // 512 entries
    float sm = smsum[t] + smsum[t + 512];      // 1024 entries
    float local = ch * (1.0f / (float)(BATCH * N_PTS))
                + sm * (0.25f / ((float)BATCH * N_PTS * KNN));
    #pragma unroll
    for (int d = 1; d < 64; d <<= 1) local += __shfl_xor(local, d, 64);
    __shared__ float wsum[8];
    if ((t & 63) == 0) wsum[t >> 6] = local;
    __syncthreads();
    if (t == 0) {
        float tot = 0.0f;
        #pragma unroll
        for (int k = 0; k < 8; ++k) tot += wsum[k];
        out[0] = tot;
    }
}

extern "C" void kernel_launch(void* const* d_in, const int* in_sizes, int n_in,
                              void* d_out, int out_size, void* d_ws, size_t ws_size,
                              hipStream_t stream) {
    const float* pc1  = (const float*)d_in[0];
    const float* pc2  = (const float*)d_in[1];
    const float* flow = (const float*)d_in[2];
    float* out = (float*)d_out;
    float* chsum = (float*)d_ws;               // 2 KiB
    float* smsum = (float*)d_ws + OFF_SMSUM;   // 4 KiB

    mega_kernel<<<dim3(NBLOCKS), 256, 0, stream>>>(pc1, pc2, flow, chsum, smsum);
    finish_kernel<<<dim3(1), 512, 0, stream>>>(chsum, smsum, out);
}